// Round 5
// baseline (401.587 us; speedup 1.0000x reference)
//
#include <hip/hip_runtime.h>
#include <cstddef>

// ============================================================================
// VLSTM via bf16 MFMA, R5: single-barrier software-pipelined step.
//  - 512 blocks x 512 threads (8 waves), 64 nodes/block, persistent T=20.
//  - Register-resident weights (96 VGPR/wave B-fragments) — R3/R4 proved this
//    beats streaming; occupancy structurally capped at 1 block/CU, so this
//    round attacks intra-step serialization instead.
//  - FULL double-buffer: Abuf[2] (emb+h, 24 KB each). Iter k reads Abuf[k&1],
//    writes h(k) + emb(k+1) into Abuf[1-(k&1)]. ONE __syncthreads per step.
//  - h also lives in per-lane regs (hcur, bf16): h-write is unconditional
//    (mask?new:old), giving masked pass-through across buffers for free.
//  - out-proj(k-1) runs at iter k reading Abuf[k&1] (same buffer as GEMM(k)),
//    masked by the saved mbits register from act(k-1); st_out/msk_s double-
//    buffered; out(k-2) stored as one coalesced 1280 B burst at iter-k top.
//  - x(k+1)/mask(k+1) prefetched into registers at iter-k top.
// ============================================================================

typedef __attribute__((ext_vector_type(8))) short  s16x8;   // 8 x bf16
typedef __attribute__((ext_vector_type(4))) float  f32x4;

namespace {
constexpr int T_STEPS = 20;
constexpr int NN      = 32768;
constexpr int D_EMB   = 64;
constexpr int D_H     = 128;
constexpr int D_OUT   = 5;
constexpr int G4      = 512;
constexpr int MT      = 64;
constexpr int BLOCK   = 512;
constexpr int GRID    = NN / MT;
constexpr int WP_ELEMS   = 8 * 4 * 6 * 64 * 8;
constexpr int WOUT_ELEMS = 4 * 64 * 8;
constexpr int AELEMS  = 24 * 64 * 8;            // shorts per A buffer
constexpr size_t OFF_H = (size_t)T_STEPS * NN * D_OUT;
constexpr size_t OFF_C = OFF_H + (size_t)NN * D_H;
}

__device__ __forceinline__ unsigned short f2bf(float x) {
    unsigned u = __float_as_uint(x);
    u = (u + 0x7FFFu + ((u >> 16) & 1u)) >> 16;     // RNE
    return (unsigned short)u;
}
__device__ __forceinline__ float bf2f(unsigned short h) {
    return __uint_as_float(((unsigned)h) << 16);
}
__device__ __forceinline__ float sigf(float x) {
    return __builtin_amdgcn_rcpf(1.0f + __expf(-x));
}
__device__ __forceinline__ float tanhf_fast(float x) {
    return fmaf(-2.0f, __builtin_amdgcn_rcpf(1.0f + __expf(2.0f * x)), 1.0f);
}

// ----------------------------------------------------------------------------
__global__ void prepack_kernel(const float* __restrict__ W_ih,
                               const float* __restrict__ b_ih,
                               const float* __restrict__ W_hh,
                               const float* __restrict__ b_hh,
                               const float* __restrict__ W_out,
                               unsigned short* __restrict__ Wp,
                               unsigned short* __restrict__ WoutF,
                               float* __restrict__ b_sum) {
    int idx = blockIdx.x * blockDim.x + threadIdx.x;
    if (idx < WP_ELEMS) {
        int j    = idx & 7;
        int L    = (idx >> 3) & 63;
        int rest = idx >> 9;
        int kb   = rest % 6;
        int gw   = rest / 6;
        int g    = gw & 3, w = gw >> 2;
        int k    = kb * 32 + (L >> 4) * 8 + j;
        int col  = g * D_H + w * 16 + (L & 15);
        float v  = (k < D_EMB) ? W_ih[k * G4 + col] : W_hh[(k - D_EMB) * G4 + col];
        Wp[idx] = f2bf(v);
    } else if (idx < WP_ELEMS + WOUT_ELEMS) {
        int i2 = idx - WP_ELEMS;
        int j = i2 & 7, L = (i2 >> 3) & 63, kb2 = i2 >> 9;
        int k = kb2 * 32 + (L >> 4) * 8 + j;
        int n = L & 15;
        WoutF[i2] = (n < D_OUT) ? f2bf(W_out[k * D_OUT + n]) : (unsigned short)0;
    }
    if (idx < G4) b_sum[idx] = b_ih[idx] + b_hh[idx];
}

// ----------------------------------------------------------------------------
__global__ __launch_bounds__(BLOCK, 2) void vlstm_kernel(
    const float* __restrict__ nodes,   // [T][N][2]
    const int*   __restrict__ mask,    // [T][N]
    const float* __restrict__ h0,      // [N][128]
    const float* __restrict__ c0,      // [N][128]
    const float* __restrict__ W_embed, // [2][64]
    const float* __restrict__ b_embed, // [64]
    const float* __restrict__ b_out,   // [5]
    const unsigned short* __restrict__ Wp,
    const unsigned short* __restrict__ WoutF,
    const float* __restrict__ b_sum,
    float* __restrict__ out)
{
    __shared__ __align__(16) unsigned short Abuf[2][AELEMS];  // 2 x 24 KB
    __shared__ __align__(16) float st_out[2][MT * D_OUT];     // 2 x 1.25 KB
    __shared__ float We_s[2 * D_EMB];
    __shared__ float be_s[D_EMB];
    __shared__ int   msk_s[2][MT];

    const int tid  = threadIdx.x;
    const int wave = tid >> 6;
    const int L    = tid & 63;
    const int quad = L >> 4;
    const int l15  = L & 15;
    const int n_base = blockIdx.x * MT;

    // ---- weights -> registers, once ----
    const unsigned short* wbase = Wp + (size_t)wave * (4 * 6 * 64 * 8);
    s16x8 Bf[4][6];
    #pragma unroll
    for (int g = 0; g < 4; g++)
        #pragma unroll
        for (int kb = 0; kb < 6; kb++)
            Bf[g][kb] = *(const s16x8*)(wbase + ((g * 6 + kb) * 64 + L) * 8);
    s16x8 WoF[4];
    #pragma unroll
    for (int kb2 = 0; kb2 < 4; kb2++)
        WoF[kb2] = *(const s16x8*)(WoutF + ((kb2 * 64) + L) * 8);

    float bias[4];
    #pragma unroll
    for (int g = 0; g < 4; g++) bias[g] = b_sum[g * D_H + wave * 16 + l15];
    const float bo = (l15 < D_OUT) ? b_out[l15] : 0.0f;

    // ---- one-time staging ----
    for (int i = tid; i < 3 * D_EMB; i += BLOCK) {
        if (i < 2 * D_EMB) We_s[i] = W_embed[i];
        else               be_s[i - 2 * D_EMB] = b_embed[i - 2 * D_EMB];
    }
    for (int i = tid; i < MT * D_H; i += BLOCK) {   // h0 -> Abuf[0] h-region
        int node = i >> 7, u = i & 127;
        int k = D_EMB + u;
        int idx = (((node >> 4) * 6 + (k >> 5)) * 64 + ((k >> 3) & 3) * 16 + (node & 15)) * 8 + (k & 7);
        Abuf[0][idx] = f2bf(h0[(size_t)(n_base + node) * D_H + u]);
    }
    const int u_lane = wave * 16 + l15;
    float c[4][4];
    unsigned short hcur[4][4];
    #pragma unroll
    for (int rt = 0; rt < 4; rt++)
        #pragma unroll
        for (int r = 0; r < 4; r++) {
            int m = rt * 16 + quad * 4 + r;
            c[rt][r]    = c0[(size_t)(n_base + m) * D_H + u_lane];
            hcur[rt][r] = f2bf(h0[(size_t)(n_base + m) * D_H + u_lane]);
        }

    const int node_e = tid >> 3;
    const int eb     = tid & 7;

    // ---- emb(0) -> Abuf[0], mask(0) -> msk_s[0] ----
    {
        const float2* xp = (const float2*)(nodes + ((size_t)0 * NN + n_base + node_e) * 2);
        float2 x = *xp;
        s16x8 ev;
        #pragma unroll
        for (int j = 0; j < 8; j++) {
            int e = eb * 8 + j;
            float v = fmaf(x.x, We_s[e], fmaf(x.y, We_s[D_EMB + e], be_s[e]));
            ev[j] = (short)f2bf(fmaxf(v, 0.0f));
        }
        int idx = (((node_e >> 4) * 6 + (eb >> 2)) * 64 + (eb & 3) * 16 + (node_e & 15)) * 8;
        *(s16x8*)(Abuf[0] + idx) = ev;
        if (tid < MT) msk_s[0][tid] = mask[(size_t)0 * NN + n_base + tid];
    }
    __syncthreads();

    // h-write address components (lane's own units)
    const int kb_u = 2 + (u_lane >> 5);
    const int fl   = ((u_lane >> 3) & 3) * 16 + quad * 4;
    const int j_u  = u_lane & 7;

    unsigned mprev = 0;

    for (int k = 0; k < T_STEPS; k++) {
        const int p = k & 1;
        const unsigned short* Ac = Abuf[p];       // read buffer (emb(k), h(k-1..))
        unsigned short*       An = Abuf[1 - p];   // write buffer (h(k), emb(k+1))
        const bool has_next = (k + 1 < T_STEPS);

        // ---- 1. prefetch x(k+1)/mask(k+1) into registers ----
        float2 xv = {0.0f, 0.0f};
        int mpf = 0;
        if (has_next) {
            xv = *(const float2*)(nodes + ((size_t)(k + 1) * NN + n_base + node_e) * 2);
            if (tid < MT) mpf = mask[(size_t)(k + 1) * NN + n_base + tid];
        }

        // ---- 2. out-proj(k-1): waves 0..3, reads Ac h-region (= h after k-1)
        if (k > 0 && wave < 4) {
            const int rt = wave;
            f32x4 ao = (f32x4){0.0f, 0.0f, 0.0f, 0.0f};
            #pragma unroll
            for (int kb2 = 0; kb2 < 4; kb2++) {
                s16x8 af = *(const s16x8*)(Ac + ((rt * 6 + 2 + kb2) * 64 + L) * 8);
                ao = __builtin_amdgcn_mfma_f32_16x16x32_bf16(af, WoF[kb2], ao, 0, 0, 0);
            }
            if (l15 < D_OUT) {
                #pragma unroll
                for (int r = 0; r < 4; r++) {
                    int node = rt * 16 + quad * 4 + r;
                    st_out[1 - p][node * D_OUT + l15] =
                        ((mprev >> (rt * 4 + r)) & 1u) ? (ao[r] + bo) : 0.0f;
                }
            }
        }

        // ---- 3. store out(k-2) (st_out[(k-2)&1] == st_out[p]) ----
        if (k > 1 && tid < MT * D_OUT)
            out[((size_t)(k - 2) * NN + n_base) * D_OUT + tid] = st_out[p][tid];

        // ---- 4. gate GEMM(k): 24 ds_read_b128 + 96 MFMA per wave ----
        f32x4 acc[4][4];
        #pragma unroll
        for (int rt = 0; rt < 4; rt++)
            #pragma unroll
            for (int g = 0; g < 4; g++)
                acc[rt][g] = (f32x4){bias[g], bias[g], bias[g], bias[g]};
        #pragma unroll
        for (int kb = 0; kb < 6; kb++) {
            #pragma unroll
            for (int rt = 0; rt < 4; rt++) {
                s16x8 af = *(const s16x8*)(Ac + ((rt * 6 + kb) * 64 + L) * 8);
                #pragma unroll
                for (int g = 0; g < 4; g++)
                    acc[rt][g] = __builtin_amdgcn_mfma_f32_16x16x32_bf16(
                        af, Bf[g][kb], acc[rt][g], 0, 0, 0);
            }
        }

        // ---- 5. activations (lane-local) + c/hcur update ----
        unsigned mbits = 0;
        #pragma unroll
        for (int rt = 0; rt < 4; rt++)
            #pragma unroll
            for (int r = 0; r < 4; r++) {
                int m = rt * 16 + quad * 4 + r;
                int mval = msk_s[p][m];
                float gi = sigf(acc[rt][0][r]);
                float gf = sigf(acc[rt][1][r]);
                float gg = tanhf_fast(acc[rt][2][r]);
                float go = sigf(acc[rt][3][r]);
                float cn = fmaf(gf, c[rt][r], gi * gg);
                float hv = go * tanhf_fast(cn);
                if (mval) {
                    c[rt][r]    = cn;
                    hcur[rt][r] = f2bf(hv);
                    mbits |= 1u << (rt * 4 + r);
                }
            }
        mprev = mbits;

        // ---- 6. h-write: all 16 (pass-through included) -> An h-region ----
        #pragma unroll
        for (int rt = 0; rt < 4; rt++)
            #pragma unroll
            for (int r = 0; r < 4; r++)
                An[((rt * 6 + kb_u) * 64 + fl + r) * 8 + j_u] = hcur[rt][r];

        // ---- 7. emb(k+1) -> An emb-region, mask(k+1) -> msk_s[1-p] ----
        if (has_next) {
            s16x8 ev;
            #pragma unroll
            for (int j = 0; j < 8; j++) {
                int e = eb * 8 + j;
                float v = fmaf(xv.x, We_s[e], fmaf(xv.y, We_s[D_EMB + e], be_s[e]));
                ev[j] = (short)f2bf(fmaxf(v, 0.0f));
            }
            int idx = (((node_e >> 4) * 6 + (eb >> 2)) * 64 + (eb & 3) * 16 + (node_e & 15)) * 8;
            *(s16x8*)(An + idx) = ev;
            if (tid < MT) msk_s[1 - p][tid] = mpf;
        }

        __syncthreads();   // the ONE barrier: An (+msk/st_out) visible for k+1
    }

    // ---- tail: out-proj(T-1) reads Abuf[T&1]; store out(T-2), out(T-1) ----
    {
        const unsigned short* Ah = Abuf[T_STEPS & 1];
        if (wave < 4) {
            const int rt = wave;
            f32x4 ao = (f32x4){0.0f, 0.0f, 0.0f, 0.0f};
            #pragma unroll
            for (int kb2 = 0; kb2 < 4; kb2++) {
                s16x8 af = *(const s16x8*)(Ah + ((rt * 6 + 2 + kb2) * 64 + L) * 8);
                ao = __builtin_amdgcn_mfma_f32_16x16x32_bf16(af, WoF[kb2], ao, 0, 0, 0);
            }
            if (l15 < D_OUT) {
                #pragma unroll
                for (int r = 0; r < 4; r++) {
                    int node = rt * 16 + quad * 4 + r;
                    st_out[(T_STEPS - 1) & 1][node * D_OUT + l15] =
                        ((mprev >> (rt * 4 + r)) & 1u) ? (ao[r] + bo) : 0.0f;
                }
            }
        }
        if (tid < MT * D_OUT)
            out[((size_t)(T_STEPS - 2) * NN + n_base) * D_OUT + tid] =
                st_out[(T_STEPS - 2) & 1][tid];
    }
    __syncthreads();
    if (tid < MT * D_OUT)
        out[((size_t)(T_STEPS - 1) * NN + n_base) * D_OUT + tid] =
            st_out[(T_STEPS - 1) & 1][tid];

    // ---- epilogue: h_fin from Abuf[T&1] (bf16), c_fin exact fp32 regs ----
    {
        const unsigned short* Ah = Abuf[T_STEPS & 1];
        for (int i = tid; i < MT * D_H; i += BLOCK) {
            int node = i >> 7, u = i & 127;
            int kk = D_EMB + u;
            int idx = (((node >> 4) * 6 + (kk >> 5)) * 64 + ((kk >> 3) & 3) * 16 + (node & 15)) * 8 + (kk & 7);
            out[OFF_H + (size_t)(n_base + node) * D_H + u] = bf2f(Ah[idx]);
        }
    }
    #pragma unroll
    for (int rt = 0; rt < 4; rt++)
        #pragma unroll
        for (int r = 0; r < 4; r++) {
            int m = rt * 16 + quad * 4 + r;
            out[OFF_C + (size_t)(n_base + m) * D_H + u_lane] = c[rt][r];
        }
}

extern "C" void kernel_launch(void* const* d_in, const int* in_sizes, int n_in,
                              void* d_out, int out_size, void* d_ws, size_t ws_size,
                              hipStream_t stream) {
    const float* nodes   = (const float*)d_in[0];
    const int*   mask    = (const int*)  d_in[1];
    const float* h0      = (const float*)d_in[2];
    const float* c0      = (const float*)d_in[3];
    const float* W_embed = (const float*)d_in[4];
    const float* b_embed = (const float*)d_in[5];
    const float* W_ih    = (const float*)d_in[6];
    const float* b_ih    = (const float*)d_in[7];
    const float* W_hh    = (const float*)d_in[8];
    const float* b_hh    = (const float*)d_in[9];
    const float* W_out   = (const float*)d_in[10];
    const float* b_out   = (const float*)d_in[11];
    float* out = (float*)d_out;

    unsigned short* Wp    = (unsigned short*)d_ws;
    unsigned short* WoutF = Wp + WP_ELEMS;
    float*          b_sum = (float*)(WoutF + WOUT_ELEMS);

    prepack_kernel<<<(WP_ELEMS + WOUT_ELEMS + 255) / 256, 256, 0, stream>>>(
        W_ih, b_ih, W_hh, b_hh, W_out, Wp, WoutF, b_sum);

    vlstm_kernel<<<GRID, BLOCK, 0, stream>>>(
        nodes, mask, h0, c0, W_embed, b_embed, b_out, Wp, WoutF, b_sum, out);
}